// Round 1
// baseline (535.660 us; speedup 1.0000x reference)
//
#include <hip/hip_runtime.h>
#include <math.h>

#define T_STEPS 1000
#define BATCH   256
#define IN_DIM  3
#define HID     512
#define OUT_DIM 2
#define BETA    0.8f
#define THRESH  1.0f
#define TAIL    10

// One thread per (b,h): runs the full T=1000 leaky-integrate-fire recurrence.
// x[:, b, :] (12 KB) staged to LDS once so the hot loop is LDS-read + ALU + store.
__global__ __launch_bounds__(256) void snn_main(const float* __restrict__ x,
                                                const float* __restrict__ W1,
                                                float* __restrict__ spk) {
    __shared__ float xs[T_STEPS * IN_DIM];  // 12 KB
    const int b     = blockIdx.x >> 1;           // 2 blocks per batch row
    const int hbase = (blockIdx.x & 1) << 8;
    const int h     = hbase + (int)threadIdx.x;

    for (int k = threadIdx.x; k < T_STEPS * IN_DIM; k += 256) {
        int t = k / 3, i = k - 3 * t;
        xs[k] = x[t * (BATCH * IN_DIM) + b * IN_DIM + i];
    }
    const float w0 = W1[h * 3 + 0];
    const float w1 = W1[h * 3 + 1];
    const float w2 = W1[h * 3 + 2];
    __syncthreads();

    float mem = 0.0f;
    float* op = spk + b * HID + h;
    #pragma unroll 4
    for (int t = 0; t < T_STEPS; ++t) {
        const float x0 = xs[t * 3 + 0];
        const float x1 = xs[t * 3 + 1];
        const float x2 = xs[t * 3 + 2];
        const float cur = fmaf(x0, w0, fmaf(x1, w1, x2 * w2));
        // snntorch Leaky, reset='zero': reset uses PREVIOUS mem
        const float keep = (mem > THRESH) ? 0.0f : 1.0f;
        mem = fmaf(BETA, mem, cur) * keep;
        op[t * (BATCH * HID)] = (mem > THRESH) ? 1.0f : 0.0f;  // == (mem-1>0)
    }
}

// avg_out[b][o] = mean over last 10 t of sigmoid( sum_h spk[t,b,h] * W2[o,h] )
// One wave per batch row; shuffle-reduce over h.
__global__ __launch_bounds__(64) void snn_tail(const float* __restrict__ spk,
                                               const float* __restrict__ W2,
                                               float* __restrict__ avg) {
    const int b    = blockIdx.x;
    const int lane = threadIdx.x;

    float w2a[8], w2b[8];
    #pragma unroll
    for (int j = 0; j < 8; ++j) {
        const int h = lane + j * 64;
        w2a[j] = W2[h];
        w2b[j] = W2[HID + h];
    }

    float acc0 = 0.0f, acc1 = 0.0f;
    for (int tt = 0; tt < TAIL; ++tt) {
        const int t = T_STEPS - TAIL + tt;
        const float* sp = spk + (size_t)t * (BATCH * HID) + b * HID;
        float s0 = 0.0f, s1 = 0.0f;
        #pragma unroll
        for (int j = 0; j < 8; ++j) {
            const float v = sp[lane + j * 64];
            s0 = fmaf(v, w2a[j], s0);
            s1 = fmaf(v, w2b[j], s1);
        }
        #pragma unroll
        for (int off = 32; off > 0; off >>= 1) {
            s0 += __shfl_down(s0, off, 64);
            s1 += __shfl_down(s1, off, 64);
        }
        if (lane == 0) {
            acc0 += 1.0f / (1.0f + expf(-s0));
            acc1 += 1.0f / (1.0f + expf(-s1));
        }
    }
    if (lane == 0) {
        avg[b * OUT_DIM + 0] = acc0 * 0.1f;
        avg[b * OUT_DIM + 1] = acc1 * 0.1f;
    }
}

extern "C" void kernel_launch(void* const* d_in, const int* in_sizes, int n_in,
                              void* d_out, int out_size, void* d_ws, size_t ws_size,
                              hipStream_t stream) {
    const float* x  = (const float*)d_in[0];   // [1000,256,3]
    const float* W1 = (const float*)d_in[1];   // [512,3]
    const float* W2 = (const float*)d_in[2];   // [2,512]
    float* out = (float*)d_out;
    float* spk = out;                                        // [1000,256,512]
    float* avg = out + (size_t)T_STEPS * BATCH * HID;        // [256,2]

    snn_main<<<dim3(BATCH * 2), dim3(256), 0, stream>>>(x, W1, spk);
    snn_tail<<<dim3(BATCH), dim3(64), 0, stream>>>(spk, W2, avg);
}

// Round 3
// 510.481 us; speedup vs baseline: 1.0493x; 1.0493x over previous
//
#include <hip/hip_runtime.h>
#include <math.h>

#define T_STEPS 1000
#define BATCH   256
#define IN_DIM  3
#define HID     512
#define OUT_DIM 2
#define BETA    0.8f
#define THRESH  1.0f
#define TAIL    10

typedef float f32x4 __attribute__((ext_vector_type(4)));

// One thread per (b, 4 consecutive h): full T=1000 LIF recurrence, float4
// non-temporal stores (1 KB per wave-store) for HBM write efficiency.
// Grid: 512 blocks x 64 threads; block = half a b-row (256 h).
__global__ __launch_bounds__(64) void snn_main(const float* __restrict__ x,
                                               const float* __restrict__ W1,
                                               float* __restrict__ spk) {
    __shared__ float xs[T_STEPS * IN_DIM];  // 12 KB: x[:, b, :]
    const int b     = blockIdx.x >> 1;
    const int hbase = (blockIdx.x & 1) << 8;      // 0 or 256
    const int h0    = hbase + (int)threadIdx.x * 4;

    for (int k = threadIdx.x; k < T_STEPS * IN_DIM; k += 64) {
        int t = k / 3, i = k - 3 * t;
        xs[k] = x[t * (BATCH * IN_DIM) + b * IN_DIM + i];
    }
    float w[4][3];
    #pragma unroll
    for (int j = 0; j < 4; ++j)
        #pragma unroll
        for (int i = 0; i < 3; ++i)
            w[j][i] = W1[(h0 + j) * 3 + i];
    __syncthreads();

    float mem[4] = {0.0f, 0.0f, 0.0f, 0.0f};
    f32x4* op = (f32x4*)(spk + (size_t)b * HID + h0);
    #pragma unroll 2
    for (int t = 0; t < T_STEPS; ++t) {
        const float x0 = xs[t * 3 + 0];
        const float x1 = xs[t * 3 + 1];
        const float x2 = xs[t * 3 + 2];
        f32x4 s;
        #pragma unroll
        for (int j = 0; j < 4; ++j) {
            const float cur = fmaf(x0, w[j][0], fmaf(x1, w[j][1], x2 * w[j][2]));
            // snntorch Leaky, reset='zero': reset uses PREVIOUS mem
            const float keep = (mem[j] > THRESH) ? 0.0f : 1.0f;
            mem[j] = fmaf(BETA, mem[j], cur) * keep;
            s[j] = (mem[j] > THRESH) ? 1.0f : 0.0f;
        }
        __builtin_nontemporal_store(s, op + (size_t)t * (BATCH * HID / 4));
    }
}

// avg_out[b][o] = mean over last 10 t of sigmoid( sum_h spk[t,b,h] * W2[o,h] )
// One block per b; 10 waves, one per tail timestep; LDS combine.
__global__ __launch_bounds__(640) void snn_tail(const float* __restrict__ spk,
                                                const float* __restrict__ W2,
                                                float* __restrict__ avg) {
    __shared__ float partial[TAIL][OUT_DIM];
    const int b    = blockIdx.x;
    const int wv   = threadIdx.x >> 6;   // 0..9 = tail index
    const int lane = threadIdx.x & 63;
    const int t    = T_STEPS - TAIL + wv;

    const float* sp = spk + (size_t)t * (BATCH * HID) + b * HID;
    float s0 = 0.0f, s1 = 0.0f;
    #pragma unroll
    for (int j = 0; j < 8; ++j) {
        const int h = lane + j * 64;
        const float v = sp[h];
        s0 = fmaf(v, W2[h], s0);
        s1 = fmaf(v, W2[HID + h], s1);
    }
    #pragma unroll
    for (int off = 32; off > 0; off >>= 1) {
        s0 += __shfl_down(s0, off, 64);
        s1 += __shfl_down(s1, off, 64);
    }
    if (lane == 0) {
        partial[wv][0] = 1.0f / (1.0f + expf(-s0));
        partial[wv][1] = 1.0f / (1.0f + expf(-s1));
    }
    __syncthreads();
    if (threadIdx.x < OUT_DIM) {
        float a = 0.0f;
        #pragma unroll
        for (int i = 0; i < TAIL; ++i) a += partial[i][threadIdx.x];
        avg[b * OUT_DIM + threadIdx.x] = a * (1.0f / TAIL);
    }
}

extern "C" void kernel_launch(void* const* d_in, const int* in_sizes, int n_in,
                              void* d_out, int out_size, void* d_ws, size_t ws_size,
                              hipStream_t stream) {
    const float* x  = (const float*)d_in[0];   // [1000,256,3]
    const float* W1 = (const float*)d_in[1];   // [512,3]
    const float* W2 = (const float*)d_in[2];   // [2,512]
    float* out = (float*)d_out;
    float* spk = out;                                        // [1000,256,512]
    float* avg = out + (size_t)T_STEPS * BATCH * HID;        // [256,2]

    snn_main<<<dim3(BATCH * 2), dim3(64), 0, stream>>>(x, W1, spk);
    snn_tail<<<dim3(BATCH), dim3(640), 0, stream>>>(spk, W2, avg);
}

// Round 4
// 504.889 us; speedup vs baseline: 1.0609x; 1.0111x over previous
//
#include <hip/hip_runtime.h>
#include <math.h>

#define T_STEPS 1000
#define BATCH   256
#define IN_DIM  3
#define HID     512
#define OUT_DIM 2
#define BETA    0.8f
#define THRESH  1.0f
#define TAIL    10

typedef float f32x4 __attribute__((ext_vector_type(4)));

// Block = 256 threads (4 waves) covering 2 adjacent batch rows (2*512 h).
// Per t the block writes 4 KB CONTIGUOUS ([t, b0, :] ++ [t, b0+1, :]).
// Grid = 128 blocks (one per CU, uniform progress) -> at any wall-clock
// instant the device writes a ~512 KB contiguous sweeping band, which is
// what the 6.2 TB/s fill kernel's access pattern looks like to HBM.
// __syncthreads every 4 t keeps the block's 4 waves time-clustered.
__global__ __launch_bounds__(256) void snn_main(const float* __restrict__ x,
                                                const float* __restrict__ W1,
                                                float* __restrict__ spk) {
    __shared__ float xs[2][T_STEPS * IN_DIM + 8];  // ~24 KB: x[:, b0, :], x[:, b0+1, :]
    const int bp   = blockIdx.x;            // b-pair index, b = 2*bp + boff
    const int flat = (int)threadIdx.x * 4;  // 0..1023 across 2 rows
    const int boff = flat >> 9;             // 0 or 1
    const int h0   = flat & 511;

    for (int k = threadIdx.x; k < 2 * T_STEPS * IN_DIM; k += 256) {
        int bb = k >= T_STEPS * IN_DIM;
        int kk = k - bb * T_STEPS * IN_DIM;
        int t = kk / 3, i = kk - 3 * t;
        xs[bb][kk] = x[t * (BATCH * IN_DIM) + (2 * bp + bb) * IN_DIM + i];
    }
    float w[4][3];
    #pragma unroll
    for (int j = 0; j < 4; ++j)
        #pragma unroll
        for (int i = 0; i < 3; ++i)
            w[j][i] = W1[(h0 + j) * 3 + i];
    __syncthreads();

    const float* xrow = xs[boff];
    float mem[4] = {0.0f, 0.0f, 0.0f, 0.0f};
    // Per-t store address: spk[t, 2*bp, 0] + flat
    f32x4* op = (f32x4*)(spk + (size_t)(2 * bp) * HID + flat);

    for (int t4 = 0; t4 < T_STEPS; t4 += 4) {
        #pragma unroll
        for (int u = 0; u < 4; ++u) {
            const int t = t4 + u;
            const float x0 = xrow[t * 3 + 0];
            const float x1 = xrow[t * 3 + 1];
            const float x2 = xrow[t * 3 + 2];
            f32x4 s;
            #pragma unroll
            for (int j = 0; j < 4; ++j) {
                const float cur = fmaf(x0, w[j][0], fmaf(x1, w[j][1], x2 * w[j][2]));
                // snntorch Leaky, reset='zero': reset uses PREVIOUS mem
                const float keep = (mem[j] > THRESH) ? 0.0f : 1.0f;
                mem[j] = fmaf(BETA, mem[j], cur) * keep;
                s[j] = (mem[j] > THRESH) ? 1.0f : 0.0f;
            }
            __builtin_nontemporal_store(s, op + (size_t)t * (BATCH * HID / 4));
        }
        __syncthreads();  // keep the 4 waves' store streams time-clustered
    }
}

// avg_out[b][o] = mean over last 10 t of sigmoid( sum_h spk[t,b,h] * W2[o,h] )
// One block per b; 10 waves, one per tail timestep; LDS combine.
__global__ __launch_bounds__(640) void snn_tail(const float* __restrict__ spk,
                                                const float* __restrict__ W2,
                                                float* __restrict__ avg) {
    __shared__ float partial[TAIL][OUT_DIM];
    const int b    = blockIdx.x;
    const int wv   = threadIdx.x >> 6;   // 0..9 = tail index
    const int lane = threadIdx.x & 63;
    const int t    = T_STEPS - TAIL + wv;

    const float* sp = spk + (size_t)t * (BATCH * HID) + b * HID;
    float s0 = 0.0f, s1 = 0.0f;
    #pragma unroll
    for (int j = 0; j < 8; ++j) {
        const int h = lane + j * 64;
        const float v = sp[h];
        s0 = fmaf(v, W2[h], s0);
        s1 = fmaf(v, W2[HID + h], s1);
    }
    #pragma unroll
    for (int off = 32; off > 0; off >>= 1) {
        s0 += __shfl_down(s0, off, 64);
        s1 += __shfl_down(s1, off, 64);
    }
    if (lane == 0) {
        partial[wv][0] = 1.0f / (1.0f + expf(-s0));
        partial[wv][1] = 1.0f / (1.0f + expf(-s1));
    }
    __syncthreads();
    if (threadIdx.x < OUT_DIM) {
        float a = 0.0f;
        #pragma unroll
        for (int i = 0; i < TAIL; ++i) a += partial[i][threadIdx.x];
        avg[b * OUT_DIM + threadIdx.x] = a * (1.0f / TAIL);
    }
}

extern "C" void kernel_launch(void* const* d_in, const int* in_sizes, int n_in,
                              void* d_out, int out_size, void* d_ws, size_t ws_size,
                              hipStream_t stream) {
    const float* x  = (const float*)d_in[0];   // [1000,256,3]
    const float* W1 = (const float*)d_in[1];   // [512,3]
    const float* W2 = (const float*)d_in[2];   // [2,512]
    float* out = (float*)d_out;
    float* spk = out;                                        // [1000,256,512]
    float* avg = out + (size_t)T_STEPS * BATCH * HID;        // [256,2]

    snn_main<<<dim3(BATCH / 2), dim3(256), 0, stream>>>(x, W1, spk);
    snn_tail<<<dim3(BATCH), dim3(640), 0, stream>>>(spk, W2, avg);
}